// Round 6
// baseline (888.581 us; speedup 1.0000x reference)
//
#include <hip/hip_runtime.h>

#define N_NODES 100000
#define N_EDGES 1600000
#define HF 128
#define BCAP 64

typedef unsigned int uint;
typedef __attribute__((ext_vector_type(8))) short short8;
typedef __attribute__((ext_vector_type(4))) float f32x4;

__device__ __forceinline__ unsigned short f2bf(float f) {
    uint u = __float_as_uint(f);
    uint r = (u + 0x7fff + ((u >> 16) & 1)) >> 16;   // RNE
    return (unsigned short)r;
}
__device__ __forceinline__ float bf2f(uint bits16) {
    return __uint_as_float(bits16 << 16);
}

// ---------------------------------------------------------------------------
// Bucket CSR build: interleaved (src, ef) entries, 4 edges/thread for MLP
// ---------------------------------------------------------------------------

__global__ void fill_bucket_kernel(const int* __restrict__ src, const int* __restrict__ dst,
                                   const float* __restrict__ ef, int* __restrict__ cur,
                                   int2* __restrict__ csef) {
    const int T = N_EDGES / 4;                       // 400000
    int i = blockIdx.x * blockDim.x + threadIdx.x;
    if (i >= T) return;                              // grid = ceil(T/256); guard tail
    int d[4], s[4]; float f[4];
    #pragma unroll
    for (int k = 0; k < 4; ++k) {
        int e = i + k * T;
        d[k] = dst[e]; s[k] = src[e]; f[k] = ef[e];
    }
    int p[4];
    #pragma unroll
    for (int k = 0; k < 4; ++k) p[k] = atomicAdd(&cur[d[k]], 1);
    #pragma unroll
    for (int k = 0; k < 4; ++k)
        if (p[k] < BCAP)
            csef[(size_t)d[k] * BCAP + p[k]] = make_int2(s[k], __float_as_int(f[k]));
}

// he[n] = sum of edge features into n (layer-invariant)
__global__ void he_kernel(const int2* __restrict__ csef, const int* __restrict__ cnt,
                          float* __restrict__ he) {
    int t = threadIdx.x;
    int node = blockIdx.x * 16 + (t >> 4);
    int gl = t & 15;
    if (node >= N_NODES) return;
    int cn = cnt[node]; if (cn > BCAP) cn = BCAP;
    const int2* bk = csef + (size_t)node * BCAP;
    float s = 0.f;
    for (int e = gl; e < cn; e += 16) s += __int_as_float(bk[e].y);
    s += __shfl_xor(s, 1); s += __shfl_xor(s, 2);
    s += __shfl_xor(s, 4); s += __shfl_xor(s, 8);
    if (gl == 0) he[node] = s;
}

// ---------------------------------------------------------------------------
// Conversions
// ---------------------------------------------------------------------------

__global__ void conv_h_kernel(const float* __restrict__ in, unsigned short* __restrict__ out) {
    int i = (blockIdx.x * 256 + threadIdx.x) * 4;   // grid covers exactly 12.8M
    float4 v = *(const float4*)(in + i);
    uint2 o;
    o.x = (uint)f2bf(v.x) | ((uint)f2bf(v.y) << 16);
    o.y = (uint)f2bf(v.z) | ((uint)f2bf(v.w) << 16);
    *(uint2*)(out + i) = o;
}

// Wt layout per layer: [kc 0..31][c 0..127][e 0..7] bf16
__global__ void conv_w_kernel(const float* __restrict__ W1, const float* __restrict__ Wmid,
                              unsigned short* __restrict__ Wt) {
    int id = blockIdx.x * 256 + threadIdx.x;      // 9*32768 = 294912
    if (id >= 9 * 32768) return;
    int layer = id >> 15;
    int rem = id & 32767;
    int kc = rem >> 10;          // 0..31
    int c  = (rem >> 3) & 127;   // 0..127
    int e  = rem & 7;            // 0..7
    const float* Wl = (layer == 0) ? W1 : Wmid + (size_t)(layer - 1) * 257 * 128;
    Wt[(size_t)layer * 32768 + rem] = f2bf(Wl[(size_t)(kc * 8 + e) * 128 + c]);
}

__global__ void conv_wcb_kernel(const float* __restrict__ W1, const float* __restrict__ b1,
                                const float* __restrict__ Wmid, const float* __restrict__ bmid,
                                float* __restrict__ wcarr, float* __restrict__ barr) {
    int id = blockIdx.x * 256 + threadIdx.x;      // 9*128 = 1152
    if (id >= 9 * 128) return;
    int layer = id >> 7, c = id & 127;
    const float* Wl = (layer == 0) ? W1 : Wmid + (size_t)(layer - 1) * 257 * 128;
    const float* bl = (layer == 0) ? b1 : bmid + (size_t)(layer - 1) * 128;
    wcarr[id] = Wl[256 * 128 + c];
    barr[id]  = bl[c];
}

// ---------------------------------------------------------------------------
// Fused layer: gather g-rows into LDS (phase A), then MFMA concat-GEMM +
// epilogue (phase B). Double-buffered h (X -> Y).
// ---------------------------------------------------------------------------

__device__ __forceinline__ void accum8(float* a, uint4 v) {
    a[0] += bf2f(v.x & 0xffffu); a[1] += bf2f(v.x >> 16);
    a[2] += bf2f(v.y & 0xffffu); a[3] += bf2f(v.y >> 16);
    a[4] += bf2f(v.z & 0xffffu); a[5] += bf2f(v.z >> 16);
    a[6] += bf2f(v.w & 0xffffu); a[7] += bf2f(v.w >> 16);
}

__launch_bounds__(256, 4)
__global__ void fused_layer_kernel(const unsigned short* __restrict__ X,
                                   unsigned short* __restrict__ Y,
                                   const int* __restrict__ cnt,
                                   const int2* __restrict__ csef,
                                   const float* __restrict__ he,
                                   const unsigned short* __restrict__ Wt,
                                   const float* __restrict__ wcarr,
                                   const float* __restrict__ barr,
                                   int mode) {
    __shared__ short gtile[128 * 128];   // 32 KB, XOR-swizzled rows
    int t = threadIdx.x;
    int row0 = blockIdx.x * 128;
    int gl = t & 15;
    const uint4* hu = (const uint4*)X;

    // ---- phase A: gather this block's 128 aggregated rows ----
    for (int pass = 0; pass < 8; ++pass) {
        int r = pass * 16 + (t >> 4);
        int node = row0 + r;
        float ax[8] = {0.f,0.f,0.f,0.f,0.f,0.f,0.f,0.f};
        float bx[8] = {0.f,0.f,0.f,0.f,0.f,0.f,0.f,0.f};
        if (node < N_NODES) {
            int cn = cnt[node]; if (cn > BCAP) cn = BCAP;
            const int2* bk = csef + (size_t)node * BCAP;
            int e = 0;
            int4 q0 = make_int4(0,0,0,0), q1 = make_int4(0,0,0,0);
            if (e + 4 <= cn) { q0 = *(const int4*)(bk + e); q1 = *(const int4*)(bk + e + 2); }
            while (e + 4 <= cn) {
                int4 c0 = q0, c1 = q1;
                int en = e + 4;
                if (en + 4 <= cn) { q0 = *(const int4*)(bk + en); q1 = *(const int4*)(bk + en + 2); }
                uint4 v0 = hu[(size_t)c0.x * 16 + gl];
                uint4 v1 = hu[(size_t)c0.z * 16 + gl];
                uint4 v2 = hu[(size_t)c1.x * 16 + gl];
                uint4 v3 = hu[(size_t)c1.z * 16 + gl];
                accum8(ax, v0); accum8(bx, v1); accum8(ax, v2); accum8(bx, v3);
                e = en;
            }
            for (; e < cn; ++e) {
                uint4 v = hu[(size_t)bk[e].x * 16 + gl];
                accum8(ax, v);
            }
        }
        uint4 o;
        o.x = (uint)f2bf(ax[0] + bx[0]) | ((uint)f2bf(ax[1] + bx[1]) << 16);
        o.y = (uint)f2bf(ax[2] + bx[2]) | ((uint)f2bf(ax[3] + bx[3]) << 16);
        o.z = (uint)f2bf(ax[4] + bx[4]) | ((uint)f2bf(ax[5] + bx[5]) << 16);
        o.w = (uint)f2bf(ax[6] + bx[6]) | ((uint)f2bf(ax[7] + bx[7]) << 16);
        int off = r * 256 + gl * 16;
        off ^= (r & 7) << 4;
        *(uint4*)((char*)gtile + off) = o;
    }
    __syncthreads();

    // ---- phase B: MFMA concat-GEMM ----
    int w = t >> 6, lane = t & 63;
    int l15 = lane & 15, l4 = lane >> 4;
    int rloc = (w >> 1) * 64;
    int rb = row0 + rloc;
    int cb = (w & 1) * 64;

    f32x4 acc[4][4] = {};

    #pragma unroll
    for (int ks = 0; ks < 8; ++ks) {
        int kk = (ks & 3) * 32 + l4 * 8;   // element offset within 128
        short8 a[4];
        if (ks < 4) {
            #pragma unroll
            for (int ra = 0; ra < 4; ++ra) {
                int row = rb + ra * 16 + l15;
                if (row > N_NODES - 1) row = N_NODES - 1;
                a[ra] = *(const short8*)((const short*)X + (size_t)row * 128 + kk);
            }
        } else {
            #pragma unroll
            for (int ra = 0; ra < 4; ++ra) {
                int r = rloc + ra * 16 + l15;
                int off = r * 256 + kk * 2;
                off ^= (r & 7) << 4;
                a[ra] = *(const short8*)((const char*)gtile + off);
            }
        }
        short8 b[4];
        const short* wt = (const short*)Wt + (size_t)(ks * 4 + l4) * 1024;
        #pragma unroll
        for (int cf = 0; cf < 4; ++cf) {
            int c = cb + cf * 16 + l15;
            b[cf] = *(const short8*)(wt + c * 8);
        }
        #pragma unroll
        for (int cf = 0; cf < 4; ++cf)
            #pragma unroll
            for (int ra = 0; ra < 4; ++ra)
                acc[ra][cf] = __builtin_amdgcn_mfma_f32_16x16x32_bf16(a[ra], b[cf], acc[ra][cf], 0, 0, 0);
    }

    // ---- epilogue: edge term + bias + activation ----
    float wcv[4], bbv[4];
    #pragma unroll
    for (int cf = 0; cf < 4; ++cf) {
        int c = cb + cf * 16 + l15;
        wcv[cf] = wcarr[c];
        bbv[cf] = barr[c];
    }
    #pragma unroll
    for (int ra = 0; ra < 4; ++ra) {
        #pragma unroll
        for (int j = 0; j < 4; ++j) {
            int row = rb + ra * 16 + l4 * 4 + j;
            if (row >= N_NODES) continue;
            float hv = he[row];
            #pragma unroll
            for (int cf = 0; cf < 4; ++cf) {
                int c = cb + cf * 16 + l15;
                float z = acc[ra][cf][j] + hv * wcv[cf] + bbv[cf];
                if (mode == 0) z += fmaxf(z, 0.f);            // relu(z)+z
                else           z = 1.f / (1.f + __expf(-z));  // sigmoid
                Y[(size_t)row * 128 + c] = f2bf(z);
            }
        }
    }
}

// ---------------------------------------------------------------------------
// Output layer via scalar trick: p[n] = h[n,:]@W2[128:256] (streaming), then
// out[n] = h[n,:]@W2[0:128] + sum_e p[src_e] + he[n]*W2[256] + b2
// ---------------------------------------------------------------------------

__global__ void dot_kernel(const unsigned short* __restrict__ h, const float* __restrict__ W2,
                           float* __restrict__ p) {
    int t = threadIdx.x;
    int node = blockIdx.x * 16 + (t >> 4);
    int gl = t & 15;
    if (node >= N_NODES) return;
    uint4 v = ((const uint4*)h)[(size_t)node * 16 + gl];
    const float* wseg = W2 + 128 + gl * 8;
    float s = bf2f(v.x & 0xffffu) * wseg[0] + bf2f(v.x >> 16) * wseg[1]
            + bf2f(v.y & 0xffffu) * wseg[2] + bf2f(v.y >> 16) * wseg[3]
            + bf2f(v.z & 0xffffu) * wseg[4] + bf2f(v.z >> 16) * wseg[5]
            + bf2f(v.w & 0xffffu) * wseg[6] + bf2f(v.w >> 16) * wseg[7];
    s += __shfl_xor(s, 1); s += __shfl_xor(s, 2);
    s += __shfl_xor(s, 4); s += __shfl_xor(s, 8);
    if (gl == 0) p[node] = s;
}

__global__ void final2_kernel(const unsigned short* __restrict__ h, const float* __restrict__ p,
                              const int* __restrict__ cnt, const int2* __restrict__ csef,
                              const float* __restrict__ he, const float* __restrict__ W2,
                              const float* __restrict__ b2, float* __restrict__ out) {
    int t = threadIdx.x;
    int node = blockIdx.x * 16 + (t >> 4);
    int gl = t & 15;
    if (node >= N_NODES) return;
    uint4 v = ((const uint4*)h)[(size_t)node * 16 + gl];
    const float* wseg = W2 + gl * 8;
    float s = bf2f(v.x & 0xffffu) * wseg[0] + bf2f(v.x >> 16) * wseg[1]
            + bf2f(v.y & 0xffffu) * wseg[2] + bf2f(v.y >> 16) * wseg[3]
            + bf2f(v.z & 0xffffu) * wseg[4] + bf2f(v.z >> 16) * wseg[5]
            + bf2f(v.w & 0xffffu) * wseg[6] + bf2f(v.w >> 16) * wseg[7];
    int cn = cnt[node]; if (cn > BCAP) cn = BCAP;
    const int2* bk = csef + (size_t)node * BCAP;
    for (int e = gl; e < cn; e += 16) s += p[bk[e].x];
    s += __shfl_xor(s, 1); s += __shfl_xor(s, 2);
    s += __shfl_xor(s, 4); s += __shfl_xor(s, 8);
    if (gl == 0) out[node] = s + he[node] * W2[256] + b2[0];
}

// ---------------------------------------------------------------------------

extern "C" void kernel_launch(void* const* d_in, const int* in_sizes, int n_in,
                              void* d_out, int out_size, void* d_ws, size_t ws_size,
                              hipStream_t stream) {
    const float* node_feat = (const float*)d_in[0];
    const float* edge_feat = (const float*)d_in[1];
    const int*   src  = (const int*)d_in[2];
    const int*   dst  = (const int*)d_in[3];
    const float* W1   = (const float*)d_in[4];
    const float* b1   = (const float*)d_in[5];
    const float* Wmid = (const float*)d_in[6];
    const float* bmid = (const float*)d_in[7];
    const float* W2   = (const float*)d_in[8];
    const float* b2   = (const float*)d_in[9];
    float* out = (float*)d_out;

    char* ws = (char*)d_ws;
    size_t off = 0;
    auto carve = [&](size_t bytes) {
        void* p = ws + off;
        off = (off + bytes + 255) & ~(size_t)255;
        return p;
    };
    int*   cur  = (int*)carve((size_t)N_NODES * 4);
    float* he   = (float*)carve((size_t)N_NODES * 4);
    int2*  csef = (int2*)carve((size_t)N_NODES * BCAP * 8);
    unsigned short* h0 = (unsigned short*)carve((size_t)N_NODES * HF * 2);
    unsigned short* h1 = (unsigned short*)carve((size_t)N_NODES * HF * 2);
    unsigned short* Wt = (unsigned short*)carve((size_t)9 * 32768 * 2);
    float* wcarr = (float*)carve((size_t)9 * 128 * 4);
    float* barr  = (float*)carve((size_t)9 * 128 * 4);
    float* pbuf  = (float*)carve((size_t)N_NODES * 4);
    (void)ws_size; (void)in_sizes; (void)n_in; (void)out_size;

    // bucket CSR + he
    hipMemsetAsync(cur, 0, (size_t)N_NODES * 4, stream);
    fill_bucket_kernel<<<dim3((N_EDGES / 4 + 255) / 256), dim3(256), 0, stream>>>(
        src, dst, edge_feat, cur, csef);
    he_kernel<<<dim3((N_NODES + 15) / 16), dim3(256), 0, stream>>>(csef, cur, he);

    // dtype conversions
    conv_h_kernel<<<dim3(12500), dim3(256), 0, stream>>>(node_feat, h0);
    conv_w_kernel<<<dim3((9 * 32768 + 255) / 256), dim3(256), 0, stream>>>(W1, Wmid, Wt);
    conv_wcb_kernel<<<dim3(5), dim3(256), 0, stream>>>(W1, b1, Wmid, bmid, wcarr, barr);

    const int gemmGrid = (N_NODES + 127) / 128;   // 782
    unsigned short* hbuf[2] = { h0, h1 };

    for (int L = 0; L < 9; ++L) {
        int mode = (L == 5 || L == 8) ? 1 : 0;
        fused_layer_kernel<<<dim3(gemmGrid), dim3(256), 0, stream>>>(
            hbuf[L & 1], hbuf[(L + 1) & 1], cur, csef, he,
            Wt + (size_t)L * 32768, wcarr + L * 128, barr + L * 128, mode);
    }
    const unsigned short* hf = hbuf[1];
    dot_kernel<<<dim3((N_NODES + 15) / 16), dim3(256), 0, stream>>>(hf, W2, pbuf);
    final2_kernel<<<dim3((N_NODES + 15) / 16), dim3(256), 0, stream>>>(
        hf, pbuf, cur, csef, he, W2, b2, out);
}